// Round 6
// baseline (187.743 us; speedup 1.0000x reference)
//
#include <hip/hip_runtime.h>
#include <hip/hip_bf16.h>
#include <cstdint>
#include <cstddef>

// Problem constants
#define B_N 8192
#define D_K 1024
#define H_N 400
#define HP  416          // H padded to multiple of 32
#define K2_N 512
#define E_N 16
#define L_N 256
#define TM 64
#define PAD_ROWS (B_N + E_N * TM)   // 9216
#define NTILES (PAD_ROWS / TM)      // 144

typedef short bf16x8 __attribute__((ext_vector_type(8)));
typedef float f32x4 __attribute__((ext_vector_type(4)));

// async global->LDS, 16B per lane; LDS dest = wave-uniform base + lane*16.
// Global address may be fully per-lane (gather OK).
#define GLDS(gp, lp) __builtin_amdgcn_global_load_lds( \
    (const __attribute__((address_space(1))) unsigned int*)(gp), \
    (__attribute__((address_space(3))) unsigned int*)(lp), 16, 0, 0)

static __device__ __forceinline__ unsigned short f2bf(float f) {
  union { float f; unsigned int u; } c; c.f = f;
  unsigned int u = c.u + 0x7fffu + ((c.u >> 16) & 1u);  // RNE
  return (unsigned short)(u >> 16);
}
static __device__ __forceinline__ unsigned int pkbf(float a, float b) {
  union { __hip_bfloat162 v; unsigned int u; } c;
  c.v = __float22bfloat162_rn(make_float2(a, b));
  return c.u;
}

// ---------------- prep (one launch, fully parallel blocks): ----------------
// [0,1792):    W1 transpose [1024][400] f32 -> [416][1024] bf16 (zero-pad)
// [1792,2688): W2 transpose [400][512] f32 -> [512][416] bf16 (zero-pad)
// [2688,3200): x convert f32 -> bf16 (16 rows/block)
// [3200,3232): partial histograms (256 samples each) + order=-1 init
//              block 3200 additionally zeroes cur0 + xc zero-row
__global__ __launch_bounds__(256) void prep_kernel(const float* __restrict__ W1,
                                                   const float* __restrict__ W2,
                                                   const float* __restrict__ x,
                                                   const int* __restrict__ idx,
                                                   unsigned short* __restrict__ Wt1,
                                                   unsigned short* __restrict__ Wt2,
                                                   unsigned short* __restrict__ xc,
                                                   int* __restrict__ hist,
                                                   int* __restrict__ cur0,
                                                   int* __restrict__ order) {
  const int bid = blockIdx.x;
  const int t = threadIdx.x;
  if (bid < 2688) {
    __shared__ unsigned short Ls[64][72];
    const float* S; unsigned short* Dt; int K, N, Kd, Nd, k0, n0;
    if (bid < 1792) {                    // W1: 16 k-blocks x 7 n-blocks x 16 e
      int e = bid / 112, r = bid % 112;
      k0 = (r % 16) * 64; n0 = (r / 16) * 64;
      S = W1 + (size_t)e * D_K * H_N; Dt = Wt1 + (size_t)e * HP * D_K;
      K = D_K; N = H_N; Kd = D_K; Nd = HP;
    } else {                             // W2: 7 k-blocks x 8 n-blocks x 16 e
      int t2 = bid - 1792; int e = t2 / 56, r = t2 % 56;
      k0 = (r % 7) * 64; n0 = (r / 7) * 64;
      S = W2 + (size_t)e * H_N * K2_N; Dt = Wt2 + (size_t)e * K2_N * HP;
      K = H_N; N = K2_N; Kd = HP; Nd = K2_N;
    }
    const int kk = t >> 4;
    const int nn = (t & 15) * 4;
    // hoist all 4 loads (independent -> MLP), then convert+write
    float4 v[4];
#pragma unroll
    for (int p = 0; p < 4; ++p) {
      int k = k0 + p * 16 + kk;
      int n = n0 + nn;
      v[p] = make_float4(0.f, 0.f, 0.f, 0.f);
      if (k < K && n + 3 < N) v[p] = *(const float4*)(S + (size_t)k * N + n);
    }
#pragma unroll
    for (int p = 0; p < 4; ++p) {
      Ls[nn + 0][p * 16 + kk] = f2bf(v[p].x);
      Ls[nn + 1][p * 16 + kk] = f2bf(v[p].y);
      Ls[nn + 2][p * 16 + kk] = f2bf(v[p].z);
      Ls[nn + 3][p * 16 + kk] = f2bf(v[p].w);
    }
    __syncthreads();
    const int n2 = t >> 3;
    const int ch = t & 7;
#pragma unroll
    for (int p = 0; p < 2; ++p) {
      int n = n0 + p * 32 + n2;
      int k = k0 + ch * 8;
      if (n < Nd && k < Kd)
        *(uint4*)(Dt + (size_t)n * Kd + k) = *(const uint4*)&Ls[p * 32 + n2][ch * 8];
    }
  } else if (bid < 3200) {
    // x convert: 16 rows per block, row-coalesced
    const int xb = bid - 2688;
    const float* S = x + (size_t)xb * 16 * D_K;
    unsigned short* Dp = xc + (size_t)xb * 16 * D_K;
#pragma unroll
    for (int i = 0; i < 16; ++i) {
      float4 v = *(const float4*)(S + i * D_K + t * 4);
      uint2 o; o.x = pkbf(v.x, v.y); o.y = pkbf(v.z, v.w);
      *(uint2*)(Dp + i * D_K + t * 4) = o;
    }
  } else {
    // partial hist (256 samples) + order init slice + (block 3200) extras
    __shared__ int h[E_N];
    const int hb = bid - 3200;
    if (t < E_N) h[t] = 0;
    __syncthreads();
    atomicAdd(&h[idx[hb * 256 + t]], 1);
    __syncthreads();
    if (t < E_N) hist[hb * E_N + t] = h[t];
    const int base = hb * (PAD_ROWS / 32);   // 288 per block
    for (int i = base + t; i < base + PAD_ROWS / 32; i += 256) order[i] = -1;
    if (hb == 0) {
      if (t < E_N) cur0[t] = 0;
      *(uint2*)(xc + (size_t)B_N * D_K + t * 4) = make_uint2(0, 0);  // zero row
    }
  }
}

// ---------------- scatter: every block computes the same prefix, then ----------
// wave-aggregated atomic scatter. Block 0 publishes off_al.
__global__ __launch_bounds__(256) void scatter_kernel(const int* __restrict__ idx,
                                                      const int* __restrict__ hist,
                                                      int* __restrict__ cur0,
                                                      int* __restrict__ off_al,
                                                      int* __restrict__ order) {
  __shared__ int offsL[E_N];
  const int t = threadIdx.x;
  __shared__ int cnt[E_N];
  if (t < E_N) {
    int s = 0;
    for (int b = 0; b < 32; ++b) s += hist[b * E_N + t];
    cnt[t] = s;
  }
  __syncthreads();
  if (t == 0) {
    int acc = 0;
    for (int e = 0; e < E_N; ++e) {
      offsL[e] = acc;
      if (blockIdx.x == 0) off_al[e] = acc;
      acc += ((cnt[e] + TM - 1) / TM) * TM;
    }
    if (blockIdx.x == 0) off_al[E_N] = acc;
  }
  __syncthreads();
  const int b = blockIdx.x * 256 + t;
  const int e = idx[b];
  const int lane = t & 63;
  const unsigned long long below = (lane == 63) ? ~0ull >> 1 : ((1ull << lane) - 1);
  int slot = 0;
#pragma unroll
  for (int ee = 0; ee < E_N; ++ee) {
    unsigned long long m = __ballot(e == ee);
    if (m != 0) {
      int leader = __ffsll((unsigned long long)m) - 1;
      int c = __popcll(m);
      int wb = 0;
      if (lane == leader) wb = atomicAdd(&cur0[ee], c);
      wb = __shfl(wb, leader, 64);
      if (e == ee) slot = offsL[ee] + wb + __popcll(m & below);
    }
  }
  order[slot] = b;
}

// ---------------- GEMM1: h1 = relu(gather(xc) @ Wt1[e]^T + b1[e]) ----------------
// grid (144,4); n-chunks of 7/7/6/6 16-col tiles. A rows DMA-gathered via order
// (pad -> zero row B_N). Dbuf LDS, XOR-swizzled 64B rows -> 2-way LDS reads.
__global__ __launch_bounds__(256) void gemm1_kernel(const unsigned short* __restrict__ xc,
                                                    const unsigned short* __restrict__ Wt1,
                                                    const float* __restrict__ b1,
                                                    const int* __restrict__ off_al,
                                                    const int* __restrict__ order,
                                                    unsigned short* __restrict__ h1buf) {
  __shared__ unsigned short As[2][64 * 32];
  __shared__ unsigned short Bs[2][112 * 32];
  __shared__ int offs[E_N + 1];
  __shared__ int rowidx[TM];
  const int tid = threadIdx.x;
  const int m0 = blockIdx.x * TM;
  const int nb = blockIdx.y;
  const int tstart = (nb < 2) ? 7 * nb : 14 + 6 * (nb - 2);
  const int tcnt   = (nb < 2) ? 7 : 6;
  if (tid <= E_N) offs[tid] = off_al[tid];
  if (tid < TM) {
    int s = order[m0 + tid];
    rowidx[tid] = (s < 0) ? B_N : s;   // pad -> zero row
  }
  __syncthreads();
  if (m0 >= offs[E_N]) return;
  int e = 0;
  while (m0 >= offs[e + 1]) ++e;
  const unsigned short* Wt1e = Wt1 + (size_t)e * HP * D_K;

  const int l = tid & 63, w = tid >> 6;
  const int r4 = l >> 2;
  const int sg = (r4 ^ (r4 >> 2)) & 3;
  const int g8 = ((l & 3) ^ sg) * 8;
  const int tl1 = w + 4;
  const unsigned short* gA  = xc + (size_t)rowidx[16 * w + r4] * D_K + g8;
  const unsigned short* gB0 = Wt1e + (size_t)((tstart + w) * 16 + r4) * D_K + g8;
  const unsigned short* gB1 = Wt1e + (size_t)((tstart + tl1) * 16 + r4) * D_K + g8;

  const int ln = l & 15, q = l >> 4;
  const int sr = (ln ^ (ln >> 2)) & 3;
  const int cq = (q ^ sr) * 8;

  f32x4 acc[4][2] = {};

  GLDS(gA, &As[0][16 * w * 32]);
  GLDS(gB0, &Bs[0][16 * w * 32]);
  if (tl1 < tcnt) GLDS(gB1, &Bs[0][16 * tl1 * 32]);

  for (int k0 = 0; k0 < D_K; k0 += 32) {
    const int cur = (k0 >> 5) & 1;
    const int nxt = cur ^ 1;
    __syncthreads();               // publishes buf[cur]
    if (k0 + 32 < D_K) {           // prefetch next; flies during compute
      GLDS(gA + k0 + 32, &As[nxt][16 * w * 32]);
      GLDS(gB0 + k0 + 32, &Bs[nxt][16 * w * 32]);
      if (tl1 < tcnt) GLDS(gB1 + k0 + 32, &Bs[nxt][16 * tl1 * 32]);
    }
    bf16x8 af[4];
#pragma unroll
    for (int i = 0; i < 4; ++i)
      af[i] = *(const bf16x8*)&As[cur][(16 * i + ln) * 32 + cq];
    {
      bf16x8 bf0 = *(const bf16x8*)&Bs[cur][(16 * w + ln) * 32 + cq];
#pragma unroll
      for (int i = 0; i < 4; ++i)
        acc[i][0] = __builtin_amdgcn_mfma_f32_16x16x32_bf16(af[i], bf0, acc[i][0], 0, 0, 0);
    }
    if (tl1 < tcnt) {
      bf16x8 bf1 = *(const bf16x8*)&Bs[cur][(16 * tl1 + ln) * 32 + cq];
#pragma unroll
      for (int i = 0; i < 4; ++i)
        acc[i][1] = __builtin_amdgcn_mfma_f32_16x16x32_bf16(af[i], bf1, acc[i][1], 0, 0, 0);
    }
  }

#pragma unroll
  for (int t = 0; t < 2; ++t) {
    const int tl = w + 4 * t;
    if (tl < tcnt) {
      const int n = (tstart + tl) * 16 + ln;
      if (n < H_N) {
        const float bias = b1[e * H_N + n];
#pragma unroll
        for (int i = 0; i < 4; ++i)
#pragma unroll
          for (int r = 0; r < 4; ++r) {
            const int m = m0 + 16 * i + 4 * q + r;
            h1buf[(size_t)m * HP + n] = f2bf(fmaxf(acc[i][t][r] + bias, 0.f));
          }
      }
    }
  }
  if (nb == 3 && tid < TM) {   // zero K-pad cols [400,416)
    uint4 z = make_uint4(0, 0, 0, 0);
    *(uint4*)&h1buf[(size_t)(m0 + tid) * HP + 400] = z;
    *(uint4*)&h1buf[(size_t)(m0 + tid) * HP + 408] = z;
  }
}

// ---------------- GEMM2: out = h1 @ Wt2[e]^T + b2[e], scatter ----------------
__global__ __launch_bounds__(256) void gemm2_kernel(const unsigned short* __restrict__ h1buf,
                                                    const unsigned short* __restrict__ Wt2,
                                                    const float* __restrict__ b2,
                                                    const int* __restrict__ off_al,
                                                    const int* __restrict__ order,
                                                    float* __restrict__ out) {
  __shared__ unsigned short As[2][64 * 32];
  __shared__ unsigned short Bs[2][128 * 32];
  __shared__ int offs[E_N + 1];
  __shared__ int rowidx[TM];
  const int tid = threadIdx.x;
  const int m0 = blockIdx.x * TM;
  const int nbase = blockIdx.y * 128;
  if (tid <= E_N) offs[tid] = off_al[tid];
  if (tid < TM) rowidx[tid] = order[m0 + tid];
  __syncthreads();
  if (m0 >= offs[E_N]) return;
  int e = 0;
  while (m0 >= offs[e + 1]) ++e;
  const unsigned short* Wt2e = Wt2 + (size_t)e * K2_N * HP;

  const int l = tid & 63, w = tid >> 6;
  const int r4 = l >> 2;
  const int sg = (r4 ^ (r4 >> 2)) & 3;
  const int g8 = ((l & 3) ^ sg) * 8;
  const int tl1 = w + 4;
  const unsigned short* gA  = h1buf + (size_t)(m0 + 16 * w + r4) * HP + g8;
  const unsigned short* gB0 = Wt2e + (size_t)(nbase + 16 * w + r4) * HP + g8;
  const unsigned short* gB1 = Wt2e + (size_t)(nbase + 16 * tl1 + r4) * HP + g8;

  const int ln = l & 15, q = l >> 4;
  const int sr = (ln ^ (ln >> 2)) & 3;
  const int cq = (q ^ sr) * 8;

  f32x4 acc[4][2] = {};

  GLDS(gA, &As[0][16 * w * 32]);
  GLDS(gB0, &Bs[0][16 * w * 32]);
  GLDS(gB1, &Bs[0][16 * tl1 * 32]);

  for (int k0 = 0; k0 < HP; k0 += 32) {   // 13 steps
    const int cur = (k0 >> 5) & 1;
    const int nxt = cur ^ 1;
    __syncthreads();
    if (k0 + 32 < HP) {
      GLDS(gA + k0 + 32, &As[nxt][16 * w * 32]);
      GLDS(gB0 + k0 + 32, &Bs[nxt][16 * w * 32]);
      GLDS(gB1 + k0 + 32, &Bs[nxt][16 * tl1 * 32]);
    }
    bf16x8 af[4];
#pragma unroll
    for (int i = 0; i < 4; ++i)
      af[i] = *(const bf16x8*)&As[cur][(16 * i + ln) * 32 + cq];
#pragma unroll
    for (int t = 0; t < 2; ++t) {
      const int tl = w + 4 * t;
      bf16x8 bfr = *(const bf16x8*)&Bs[cur][(16 * tl + ln) * 32 + cq];
#pragma unroll
      for (int i = 0; i < 4; ++i)
        acc[i][t] = __builtin_amdgcn_mfma_f32_16x16x32_bf16(af[i], bfr, acc[i][t], 0, 0, 0);
    }
  }

#pragma unroll
  for (int t = 0; t < 2; ++t) {
    const int tl = w + 4 * t;
    const int n = nbase + 16 * tl + ln;
    const float bias = b2[e * K2_N + n];
#pragma unroll
    for (int i = 0; i < 4; ++i)
#pragma unroll
      for (int r = 0; r < 4; ++r) {
        const int s = rowidx[16 * i + 4 * q + r];
        if (s >= 0) {
          const float v = acc[i][t][r] + bias;
          if (n < L_N) out[(size_t)s * L_N + n] = v;
          else         out[(size_t)(B_N + s) * L_N + (n - L_N)] = v;
        }
      }
  }
}

extern "C" void kernel_launch(void* const* d_in, const int* in_sizes, int n_in,
                              void* d_out, int out_size, void* d_ws, size_t ws_size,
                              hipStream_t stream) {
  const float* x   = (const float*)d_in[0];
  const int*   idx = (const int*)d_in[1];
  const float* W1  = (const float*)d_in[2];
  const float* b1  = (const float*)d_in[3];
  const float* W2  = (const float*)d_in[4];
  const float* b2  = (const float*)d_in[5];
  float* out = (float*)d_out;

  // ws layout (bytes), total ~44.9 MB:
  // off_al@0 (68) | cur0@128 (64) | hist@192 (2048) | order@2240 (36864)
  // xc@39104 ((8192+1)x1024x2 = 16,779,264) | h1@16,818,368 (7,667,712)
  // Wt1@24,486,080 (13,631,488) | Wt2@38,117,568 (6,815,744) -> 44,933,312
  char* ws = (char*)d_ws;
  int* off_al = (int*)(ws + 0);
  int* cur0   = (int*)(ws + 128);
  int* hist   = (int*)(ws + 192);
  int* order  = (int*)(ws + 2240);
  unsigned short* xc  = (unsigned short*)(ws + 39104);
  unsigned short* h1  = (unsigned short*)(ws + 16818368);
  unsigned short* Wt1 = (unsigned short*)(ws + 24486080);
  unsigned short* Wt2 = (unsigned short*)(ws + 38117568);

  prep_kernel<<<3232, 256, 0, stream>>>(W1, W2, x, idx, Wt1, Wt2, xc, hist, cur0, order);
  scatter_kernel<<<32, 256, 0, stream>>>(idx, hist, cur0, off_al, order);
  gemm1_kernel<<<dim3(NTILES, 4), 256, 0, stream>>>(xc, Wt1, b1, off_al, order, h1);
  gemm2_kernel<<<dim3(NTILES, 4), 256, 0, stream>>>(h1, Wt2, b2, off_al, order, out);
}

// Round 7
// 160.557 us; speedup vs baseline: 1.1693x; 1.1693x over previous
//
#include <hip/hip_runtime.h>
#include <hip/hip_bf16.h>
#include <cstdint>
#include <cstddef>

// Problem constants
#define B_N 8192
#define D_K 1024
#define H_N 400
#define HP  416          // H padded to multiple of 32
#define K2_N 512
#define E_N 16
#define L_N 256
#define TM 64
#define PAD_ROWS (B_N + E_N * TM)   // 9216
#define NTILES (PAD_ROWS / TM)      // 144

typedef short bf16x8 __attribute__((ext_vector_type(8)));
typedef float f32x4 __attribute__((ext_vector_type(4)));

// async global->LDS, 16B per lane; LDS dest = wave-uniform base + lane*16.
// Global address may be fully per-lane (gather OK).
#define GLDS(gp, lp) __builtin_amdgcn_global_load_lds( \
    (const __attribute__((address_space(1))) unsigned int*)(gp), \
    (__attribute__((address_space(3))) unsigned int*)(lp), 16, 0, 0)

static __device__ __forceinline__ unsigned short f2bf(float f) {
  union { float f; unsigned int u; } c; c.f = f;
  unsigned int u = c.u + 0x7fffu + ((c.u >> 16) & 1u);  // RNE
  return (unsigned short)(u >> 16);
}
static __device__ __forceinline__ unsigned int pkbf(float a, float b) {
  union { __hip_bfloat162 v; unsigned int u; } c;
  c.v = __float22bfloat162_rn(make_float2(a, b));
  return c.u;
}

// ---------------- hist: 32 blocks x 256 samples -> partial histograms -------
__global__ __launch_bounds__(256) void hist_kernel(const int* __restrict__ idx,
                                                   int* __restrict__ hist) {
  __shared__ int h[E_N];
  const int t = threadIdx.x;
  if (t < E_N) h[t] = 0;
  __syncthreads();
  atomicAdd(&h[idx[blockIdx.x * 256 + t]], 1);
  __syncthreads();
  if (t < E_N) hist[blockIdx.x * E_N + t] = h[t];
}

// ---------------- prep (one launch, fully parallel blocks): ----------------
// [0,1792):    W1 transpose [1024][400] f32 -> [416][1024] bf16 (zero-pad)
// [1792,2688): W2 transpose [400][512] f32 -> [512][416] bf16 (zero-pad)
// [2688,3200): x convert f32 -> bf16 (16 rows/block)
// [3200,3232): scatter: block hb places samples [hb*256,hb*256+256) using
//              deterministic base = offs[e] + prefix(hist[<hb][e]); LDS atomics
//              only. hb==0 also publishes off_al/cnt_al + zeroes xc pad row.
__global__ __launch_bounds__(256) void prep_kernel(const float* __restrict__ W1,
                                                   const float* __restrict__ W2,
                                                   const float* __restrict__ x,
                                                   const int* __restrict__ idx,
                                                   const int* __restrict__ hist,
                                                   unsigned short* __restrict__ Wt1,
                                                   unsigned short* __restrict__ Wt2,
                                                   unsigned short* __restrict__ xc,
                                                   int* __restrict__ off_al,
                                                   int* __restrict__ cnt_al,
                                                   int* __restrict__ order) {
  const int bid = blockIdx.x;
  const int t = threadIdx.x;
  if (bid < 2688) {
    __shared__ unsigned short Ls[64][72];
    const float* S; unsigned short* Dt; int K, N, Kd, Nd, k0, n0;
    if (bid < 1792) {                    // W1: 16 k-blocks x 7 n-blocks x 16 e
      int e = bid / 112, r = bid % 112;
      k0 = (r % 16) * 64; n0 = (r / 16) * 64;
      S = W1 + (size_t)e * D_K * H_N; Dt = Wt1 + (size_t)e * HP * D_K;
      K = D_K; N = H_N; Kd = D_K; Nd = HP;
    } else {                             // W2: 7 k-blocks x 8 n-blocks x 16 e
      int t2 = bid - 1792; int e = t2 / 56, r = t2 % 56;
      k0 = (r % 7) * 64; n0 = (r / 7) * 64;
      S = W2 + (size_t)e * H_N * K2_N; Dt = Wt2 + (size_t)e * K2_N * HP;
      K = H_N; N = K2_N; Kd = HP; Nd = K2_N;
    }
    const int kk = t >> 4;
    const int nn = (t & 15) * 4;
    float4 v[4];
#pragma unroll
    for (int p = 0; p < 4; ++p) {
      int k = k0 + p * 16 + kk;
      int n = n0 + nn;
      v[p] = make_float4(0.f, 0.f, 0.f, 0.f);
      if (k < K && n + 3 < N) v[p] = *(const float4*)(S + (size_t)k * N + n);
    }
#pragma unroll
    for (int p = 0; p < 4; ++p) {
      Ls[nn + 0][p * 16 + kk] = f2bf(v[p].x);
      Ls[nn + 1][p * 16 + kk] = f2bf(v[p].y);
      Ls[nn + 2][p * 16 + kk] = f2bf(v[p].z);
      Ls[nn + 3][p * 16 + kk] = f2bf(v[p].w);
    }
    __syncthreads();
    const int n2 = t >> 3;
    const int ch = t & 7;
#pragma unroll
    for (int p = 0; p < 2; ++p) {
      int n = n0 + p * 32 + n2;
      int k = k0 + ch * 8;
      if (n < Nd && k < Kd)
        *(uint4*)(Dt + (size_t)n * Kd + k) = *(const uint4*)&Ls[p * 32 + n2][ch * 8];
    }
  } else if (bid < 3200) {
    const int xb = bid - 2688;
    const float* S = x + (size_t)xb * 16 * D_K;
    unsigned short* Dp = xc + (size_t)xb * 16 * D_K;
#pragma unroll
    for (int i = 0; i < 16; ++i) {
      float4 v = *(const float4*)(S + i * D_K + t * 4);
      uint2 o; o.x = pkbf(v.x, v.y); o.y = pkbf(v.z, v.w);
      *(uint2*)(Dp + i * D_K + t * 4) = o;
    }
  } else {
    const int hb = bid - 3200;
    __shared__ int totL[E_N], preL[E_N], offsL[E_N], curL[E_N];
    if (t < E_N) {
      int pre = 0, tot = 0;
      for (int b = 0; b < 32; ++b) {
        int h = hist[b * E_N + t];
        if (b < hb) pre += h;
        tot += h;
      }
      totL[t] = tot; preL[t] = pre;
    }
    __syncthreads();
    if (t == 0) {
      int acc = 0;
      for (int e = 0; e < E_N; ++e) {
        offsL[e] = acc;
        if (hb == 0) off_al[e] = acc;
        acc += ((totL[e] + TM - 1) / TM) * TM;
      }
      if (hb == 0) off_al[E_N] = acc;
    }
    __syncthreads();
    if (t < E_N) {
      curL[t] = offsL[t] + preL[t];
      if (hb == 0) cnt_al[t] = totL[t];
    }
    __syncthreads();
    const int b = hb * 256 + t;
    const int e = idx[b];
    const int slot = atomicAdd(&curL[e], 1);
    order[slot] = b;
    if (hb == 0) *(uint2*)(xc + (size_t)B_N * D_K + t * 4) = make_uint2(0, 0);
  }
}

// ---------------- GEMM1: h1 = relu(gather(xc) @ Wt1[e]^T + b1[e]) ----------------
// grid (144,7); chunks of {4,4,4,4,4,3,3} 16-col tiles; wave w owns tile w.
// A rows DMA-gathered via order (pad slots -> zero row B_N).
// XOR-swizzled 64B LDS rows -> 2-way bank reads; dbuf + 1-step DMA prefetch.
__global__ __launch_bounds__(256) void gemm1_kernel(const unsigned short* __restrict__ xc,
                                                    const unsigned short* __restrict__ Wt1,
                                                    const float* __restrict__ b1,
                                                    const int* __restrict__ off_al,
                                                    const int* __restrict__ cnt_al,
                                                    const int* __restrict__ order,
                                                    unsigned short* __restrict__ h1buf) {
  __shared__ unsigned short As[2][64 * 32];
  __shared__ unsigned short Bs[2][64 * 32];
  __shared__ int offs[E_N + 1];
  __shared__ int rowidx[TM];
  const int tid = threadIdx.x;
  const int m0 = blockIdx.x * TM;
  const int nb = blockIdx.y;
  const int tstart = (nb < 5) ? 4 * nb : 20 + 3 * (nb - 5);
  const int tcnt   = (nb < 5) ? 4 : 3;
  if (tid <= E_N) offs[tid] = off_al[tid];
  __syncthreads();
  if (m0 >= offs[E_N]) return;
  int e = 0;
  while (m0 >= offs[e + 1]) ++e;
  if (tid < TM) {
    const bool valid = (m0 + tid) < (offs[e] + cnt_al[e]);
    rowidx[tid] = valid ? order[m0 + tid] : B_N;   // pad -> zero row
  }
  __syncthreads();
  const unsigned short* Wt1e = Wt1 + (size_t)e * HP * D_K;

  const int l = tid & 63, w = tid >> 6;
  const int r4 = l >> 2;
  const int sg = (r4 ^ (r4 >> 2)) & 3;
  const int g8 = ((l & 3) ^ sg) * 8;
  const bool wact = (w < tcnt);
  const unsigned short* gA = xc + (size_t)rowidx[16 * w + r4] * D_K + g8;
  const unsigned short* gB = Wt1e + (size_t)((tstart + w) * 16 + r4) * D_K + g8;

  const int ln = l & 15, q = l >> 4;
  const int sr = (ln ^ (ln >> 2)) & 3;
  const int cq = (q ^ sr) * 8;

  f32x4 acc[4] = {};

  GLDS(gA, &As[0][16 * w * 32]);
  if (wact) GLDS(gB, &Bs[0][16 * w * 32]);

  for (int k0 = 0; k0 < D_K; k0 += 32) {
    const int cur = (k0 >> 5) & 1;
    const int nxt = cur ^ 1;
    __syncthreads();               // publishes buf[cur]
    if (k0 + 32 < D_K) {
      GLDS(gA + k0 + 32, &As[nxt][16 * w * 32]);
      if (wact) GLDS(gB + k0 + 32, &Bs[nxt][16 * w * 32]);
    }
    if (wact) {
      bf16x8 af[4];
#pragma unroll
      for (int i = 0; i < 4; ++i)
        af[i] = *(const bf16x8*)&As[cur][(16 * i + ln) * 32 + cq];
      bf16x8 bfr = *(const bf16x8*)&Bs[cur][(16 * w + ln) * 32 + cq];
#pragma unroll
      for (int i = 0; i < 4; ++i)
        acc[i] = __builtin_amdgcn_mfma_f32_16x16x32_bf16(af[i], bfr, acc[i], 0, 0, 0);
    }
  }

  if (wact) {
    const int n = (tstart + w) * 16 + ln;
    if (n < H_N) {
      const float bias = b1[e * H_N + n];
#pragma unroll
      for (int i = 0; i < 4; ++i)
#pragma unroll
        for (int r = 0; r < 4; ++r) {
          const int m = m0 + 16 * i + 4 * q + r;
          h1buf[(size_t)m * HP + n] = f2bf(fmaxf(acc[i][r] + bias, 0.f));
        }
    }
  }
  // h1 pad cols [400,416) stay unwritten: Wt2 rows there are zero, so the
  // poison contributes exactly 0 to gemm2 (finite denormal x 0).
}

// ---------------- GEMM2: out = h1 @ Wt2[e]^T + b2[e], scatter ----------------
// grid (144,8); 4 tiles/chunk exact; wave w owns tile 4*nb+w. K=416, 13 steps.
__global__ __launch_bounds__(256) void gemm2_kernel(const unsigned short* __restrict__ h1buf,
                                                    const unsigned short* __restrict__ Wt2,
                                                    const float* __restrict__ b2,
                                                    const int* __restrict__ off_al,
                                                    const int* __restrict__ cnt_al,
                                                    const int* __restrict__ order,
                                                    float* __restrict__ out) {
  __shared__ unsigned short As[2][64 * 32];
  __shared__ unsigned short Bs[2][64 * 32];
  __shared__ int offs[E_N + 1];
  __shared__ int rowidx[TM];
  const int tid = threadIdx.x;
  const int m0 = blockIdx.x * TM;
  const int nb = blockIdx.y;
  if (tid <= E_N) offs[tid] = off_al[tid];
  __syncthreads();
  if (m0 >= offs[E_N]) return;
  int e = 0;
  while (m0 >= offs[e + 1]) ++e;
  if (tid < TM) {
    const bool valid = (m0 + tid) < (offs[e] + cnt_al[e]);
    rowidx[tid] = valid ? order[m0 + tid] : -1;
  }
  __syncthreads();
  const unsigned short* Wt2e = Wt2 + (size_t)e * K2_N * HP;

  const int l = tid & 63, w = tid >> 6;
  const int r4 = l >> 2;
  const int sg = (r4 ^ (r4 >> 2)) & 3;
  const int g8 = ((l & 3) ^ sg) * 8;
  const unsigned short* gA = h1buf + (size_t)(m0 + 16 * w + r4) * HP + g8;
  const unsigned short* gB = Wt2e + (size_t)((4 * nb + w) * 16 + r4) * HP + g8;

  const int ln = l & 15, q = l >> 4;
  const int sr = (ln ^ (ln >> 2)) & 3;
  const int cq = (q ^ sr) * 8;

  f32x4 acc[4] = {};

  GLDS(gA, &As[0][16 * w * 32]);
  GLDS(gB, &Bs[0][16 * w * 32]);

  for (int k0 = 0; k0 < HP; k0 += 32) {   // 13 steps
    const int cur = (k0 >> 5) & 1;
    const int nxt = cur ^ 1;
    __syncthreads();
    if (k0 + 32 < HP) {
      GLDS(gA + k0 + 32, &As[nxt][16 * w * 32]);
      GLDS(gB + k0 + 32, &Bs[nxt][16 * w * 32]);
    }
    bf16x8 af[4];
#pragma unroll
    for (int i = 0; i < 4; ++i)
      af[i] = *(const bf16x8*)&As[cur][(16 * i + ln) * 32 + cq];
    bf16x8 bfr = *(const bf16x8*)&Bs[cur][(16 * w + ln) * 32 + cq];
#pragma unroll
    for (int i = 0; i < 4; ++i)
      acc[i] = __builtin_amdgcn_mfma_f32_16x16x32_bf16(af[i], bfr, acc[i], 0, 0, 0);
  }

  const int n = (4 * nb + w) * 16 + ln;
  const float bias = b2[e * K2_N + n];
#pragma unroll
  for (int i = 0; i < 4; ++i)
#pragma unroll
    for (int r = 0; r < 4; ++r) {
      const int s = rowidx[16 * i + 4 * q + r];
      if (s >= 0) {
        const float v = acc[i][r] + bias;
        if (n < L_N) out[(size_t)s * L_N + n] = v;
        else         out[(size_t)(B_N + s) * L_N + (n - L_N)] = v;
      }
    }
}

extern "C" void kernel_launch(void* const* d_in, const int* in_sizes, int n_in,
                              void* d_out, int out_size, void* d_ws, size_t ws_size,
                              hipStream_t stream) {
  const float* x   = (const float*)d_in[0];
  const int*   idx = (const int*)d_in[1];
  const float* W1  = (const float*)d_in[2];
  const float* b1  = (const float*)d_in[3];
  const float* W2  = (const float*)d_in[4];
  const float* b2  = (const float*)d_in[5];
  float* out = (float*)d_out;

  // ws layout (bytes), total ~44.9 MB:
  // off_al@0 (68) | cnt_al@128 (64) | hist@192 (2048) | order@2240 (36864)
  // xc@39104 ((8192+1)x1024x2) | h1@16,818,368 (9216x416x2)
  // Wt1@24,486,080 (16x416x1024x2) | Wt2@38,117,568 (16x512x416x2) -> 44,933,312
  char* ws = (char*)d_ws;
  int* off_al = (int*)(ws + 0);
  int* cnt_al = (int*)(ws + 128);
  int* hist   = (int*)(ws + 192);
  int* order  = (int*)(ws + 2240);
  unsigned short* xc  = (unsigned short*)(ws + 39104);
  unsigned short* h1  = (unsigned short*)(ws + 16818368);
  unsigned short* Wt1 = (unsigned short*)(ws + 24486080);
  unsigned short* Wt2 = (unsigned short*)(ws + 38117568);

  hist_kernel<<<32, 256, 0, stream>>>(idx, hist);
  prep_kernel<<<3232, 256, 0, stream>>>(W1, W2, x, idx, hist, Wt1, Wt2, xc,
                                        off_al, cnt_al, order);
  gemm1_kernel<<<dim3(NTILES, 7), 256, 0, stream>>>(xc, Wt1, b1, off_al, cnt_al, order, h1);
  gemm2_kernel<<<dim3(NTILES, 8), 256, 0, stream>>>(h1, Wt2, b2, off_al, cnt_al, order, out);
}